// Round 9
// baseline (238.619 us; speedup 1.0000x reference)
//
#include <hip/hip_runtime.h>
#include <hip/hip_bf16.h>
#include <math.h>

typedef __bf16 bf16_t;
typedef __bf16 bf16x4_t __attribute__((ext_vector_type(4)));
typedef __bf16 bf16x8_t __attribute__((ext_vector_type(8)));
typedef float  f32x4_t  __attribute__((ext_vector_type(4)));

#define SEQ 2048
#define DM  1024
#define NH  16
#define DK  64
// log2(10000)/32
#define ROPE_C 0.4152410118609203f
// log2(e)/sqrt(dk)
#define EXP_C (1.4426950408889634f / 8.0f)

// async global->LDS, 16B per lane; LDS dst = base + lane*16 (wave-uniform base)
#define GLD16(gp, lp) \
  __builtin_amdgcn_global_load_lds((__attribute__((address_space(1))) const void*)(gp), \
                                   (__attribute__((address_space(3))) void*)(lp), 16, 0, 0)

// ---------------- fused prep: fp32->bf16 cast (x,wq,wk,wv,wo) + RoPE LUT ----
__global__ __launch_bounds__(256)
void prep_kernel(const float* __restrict__ x,  const float* __restrict__ wq,
                 const float* __restrict__ wk, const float* __restrict__ wv,
                 const float* __restrict__ wo, bf16_t* __restrict__ dst,
                 float2* __restrict__ lut) {
  if (blockIdx.x < 8192) {
    int i = blockIdx.x * 256 + threadIdx.x;   // float4 index, 0..2097151
    const float* s;
    if (i < 1048576) {
      s = x + (size_t)i * 4;
    } else {
      int j = i - 1048576;
      int w = j >> 18;                        // 262144 float4 per weight
      const float* base = (w == 0) ? wq : (w == 1) ? wk : (w == 2) ? wv : wo;
      s = base + (size_t)(j & 262143) * 4;
    }
    float4 v = *(const float4*)s;
    bf16x4_t o;
    o.x = (bf16_t)v.x; o.y = (bf16_t)v.y; o.z = (bf16_t)v.z; o.w = (bf16_t)v.w;
    ((bf16x4_t*)dst)[i] = o;
  } else {
    int i = (blockIdx.x - 8192) * 256 + threadIdx.x;  // 0..65535
    int s = i >> 5, f = i & 31;
    float ang = (float)s * exp2f(-ROPE_C * (float)f);
    float sn, cs;
    sincosf(ang, &sn, &cs);
    lut[i] = make_float2(sn, cs);
  }
}

// ---------------- fused Q/K/V GEMM: BK=64, swizzled LDS, 768 blocks --------
// (unchanged from R6)
__global__ __launch_bounds__(256, 3)
void gemm_qkv(const bf16_t* __restrict__ A, const bf16_t* __restrict__ Wq,
              const bf16_t* __restrict__ Wk, const bf16_t* __restrict__ Wv,
              const float* __restrict__ bq, const float* __restrict__ bk,
              const float* __restrict__ bv, const float2* __restrict__ lut,
              bf16_t* __restrict__ Qb, bf16_t* __restrict__ Kb,
              bf16_t* __restrict__ Vtb) {
  const int K = 1024;
  __shared__ bf16_t As[128 * 64];           // 16 KB, granule-swizzled
  __shared__ bf16_t Bs[128 * 64];           // 16 KB

  const int tid  = threadIdx.x;
  const int w    = tid >> 6;                // 0..3
  const int lane = tid & 63;
  const int quad = lane >> 4;
  const int lrow = lane & 15;
  const int wm = (w >> 1) * 64, wn = (w & 1) * 64;

  const int srow8 = lane >> 3;                        // 0..7
  const int scolz = (((lane & 7) ^ (lane >> 3)) * 8); // pre-swizzled col

  const int id   = blockIdx.x;              // 0..767
  const int xcd  = id & 7;
  const int rank = id >> 3;                 // 0..95
  const int isV  = rank >= 64;              // block-uniform

  const bf16_t* Ablk;
  const bf16_t* Bblk;
  int bmQK = 0, bnl = 0, isK = 0, bmF = 0, bnT = 0;
  if (!isV) {
    const int q = xcd * 64 + rank;          // 0..511
    bmQK = q >> 4;                          // token tile, [xcd*4, xcd*4+4)
    const int bn = q & 15;
    isK = bn >> 3;                          // 0 = Q, 1 = K
    bnl = bn & 7;
    Ablk = A + (size_t)(bmQK * 128) * K;
    Bblk = (isK ? Wk : Wq) + (size_t)(bnl * 128) * K;
  } else {
    const int v = xcd * 32 + (rank - 64);   // 0..255
    bnT = v >> 3;                           // token tile, [xcd*4, xcd*4+4)
    bmF = v & 7;                            // feature tile 0..7
    Ablk = Wv + (size_t)(bmF * 128) * K;    // 128 feature rows
    Bblk = A + (size_t)(bnT * 128) * K;     // 128 token rows
  }

  f32x4_t acc[4][4] = {};

  for (int k0 = 0; k0 < K; k0 += 64) {
#pragma unroll
    for (int i = 0; i < 4; i++) {
      GLD16(&Ablk[(size_t)(w * 32 + i * 8 + srow8) * K + k0 + scolz], &As[(w * 32 + i * 8) * 64]);
      GLD16(&Bblk[(size_t)(w * 32 + i * 8 + srow8) * K + k0 + scolz], &Bs[(w * 32 + i * 8) * 64]);
    }
    __syncthreads();

#pragma unroll
    for (int kk = 0; kk < 2; kk++) {
      const int gsw = (((kk << 2) | quad) ^ (lrow & 7)) * 8;  // swizzled granule
      bf16x8_t af[4], bf[4];
#pragma unroll
      for (int mi = 0; mi < 4; mi++)
        af[mi] = *(const bf16x8_t*)(&As[(wm + mi * 16 + lrow) * 64 + gsw]);
#pragma unroll
      for (int ni = 0; ni < 4; ni++)
        bf[ni] = *(const bf16x8_t*)(&Bs[(wn + ni * 16 + lrow) * 64 + gsw]);
#pragma unroll
      for (int mi = 0; mi < 4; mi++)
#pragma unroll
        for (int ni = 0; ni < 4; ni++)
          acc[mi][ni] = __builtin_amdgcn_mfma_f32_16x16x32_bf16(af[mi], bf[ni], acc[mi][ni], 0, 0, 0);
    }
    __syncthreads();
  }

  if (!isV) {
    const int brow = bmQK * 128 + wm;
    const int cbase = bnl * 128 + wn;
    const float* bias = isK ? bk : bq;
    bf16_t* D = isK ? Kb : Qb;

#pragma unroll
    for (int ni = 0; ni < 4; ni++) {
      const int col = cbase + ni * 16 + lrow;  // 0..1023
      const float bvv = bias[col];
      const int t = col & 63;
      const int h = col >> 6;
      const int fidx = t >> 1;
#pragma unroll
      for (int mi = 0; mi < 4; mi++) {
        f32x4_t v = acc[mi][ni];
#pragma unroll
        for (int r = 0; r < 4; r++) {
          const int row = brow + mi * 16 + quad * 4 + r;  // token
          const int s = row & (SEQ - 1);
          float val = v[r] + bvv;
          const float2 sc = lut[s * 32 + fidx];
          const float pv = __shfl_xor(val, 1);            // partner column col^1
          val = (t & 1) ? (val * sc.y + pv * sc.x) : (val * sc.y - pv * sc.x);
          const int b = row >> 11;
          const size_t o = (((size_t)(b * NH + h) * SEQ) + s) * DK + t;
          D[o] = (bf16_t)val;
        }
      }
    }
  } else {
    const int fbase = bmF * 128 + wm;
    const int tbase = bnT * 128 + wn;

#pragma unroll
    for (int ni = 0; ni < 4; ni++) {
      const int t = tbase + ni * 16 + lrow;    // token
      const int b = t >> 11;
      const int s = t & (SEQ - 1);
#pragma unroll
      for (int mi = 0; mi < 4; mi++) {
        f32x4_t v = acc[mi][ni];
        const int f = fbase + mi * 16 + quad * 4;  // feature base (mult of 4)
        const int h = f >> 6, d = f & 63;          // d+3 <= 63, never crosses head
#pragma unroll
        for (int r = 0; r < 4; r++)
          Vtb[((size_t)((b * NH + h) * DK + d + r)) * SEQ + s] = (bf16_t)(v[r] + bv[f + r]);
      }
    }
  }
}

// ---------------- output GEMM: BK=64 swizzled (unchanged from R7/R8) -------
__global__ __launch_bounds__(256)
void gemm_out(const bf16_t* __restrict__ A, const bf16_t* __restrict__ Bw,
              const float* __restrict__ bias, float* __restrict__ D) {
  const int K = 1024;
  __shared__ bf16_t As[128 * 64];
  __shared__ bf16_t Bs[64 * 64];

  const int tid  = threadIdx.x;
  const int w    = tid >> 6;                // 0..3
  const int lane = tid & 63;
  const int quad = lane >> 4;
  const int lrow = lane & 15;
  const int wm = (w >> 1) * 64, wn = (w & 1) * 32;

  const int srow8 = lane >> 3;                        // 0..7
  const int scolz = (((lane & 7) ^ (lane >> 3)) * 8); // pre-swizzled col

  const int id  = blockIdx.x;               // 0..511
  const int swz = (id & 7) * 64 + (id >> 3);
  const int bm  = swz >> 4;                 // 0..31
  const int bn  = swz & 15;                 // 0..15

  const bf16_t* Ablk = A  + (size_t)(bm * 128) * K;
  const bf16_t* Bblk = Bw + (size_t)(bn * 64) * K;

  f32x4_t acc[4][2] = {};

  for (int k0 = 0; k0 < K; k0 += 64) {
#pragma unroll
    for (int i = 0; i < 4; i++)
      GLD16(&Ablk[(size_t)(w * 32 + i * 8 + srow8) * K + k0 + scolz], &As[(w * 32 + i * 8) * 64]);
#pragma unroll
    for (int i = 0; i < 2; i++)
      GLD16(&Bblk[(size_t)(w * 16 + i * 8 + srow8) * K + k0 + scolz], &Bs[(w * 16 + i * 8) * 64]);
    __syncthreads();

#pragma unroll
    for (int kk = 0; kk < 2; kk++) {
      const int gsw = (((kk << 2) | quad) ^ (lrow & 7)) * 8;
      bf16x8_t af[4], bf[2];
#pragma unroll
      for (int mi = 0; mi < 4; mi++)
        af[mi] = *(const bf16x8_t*)(&As[(wm + mi * 16 + lrow) * 64 + gsw]);
#pragma unroll
      for (int ni = 0; ni < 2; ni++)
        bf[ni] = *(const bf16x8_t*)(&Bs[(wn + ni * 16 + lrow) * 64 + gsw]);
#pragma unroll
      for (int mi = 0; mi < 4; mi++)
#pragma unroll
        for (int ni = 0; ni < 2; ni++)
          acc[mi][ni] = __builtin_amdgcn_mfma_f32_16x16x32_bf16(af[mi], bf[ni], acc[mi][ni], 0, 0, 0);
    }
    __syncthreads();
  }

#pragma unroll
  for (int ni = 0; ni < 2; ni++) {
    const int col = bn * 64 + wn + ni * 16 + lrow;
    const float bvv = bias[col];
#pragma unroll
    for (int mi = 0; mi < 4; mi++) {
      f32x4_t v = acc[mi][ni];
#pragma unroll
      for (int r = 0; r < 4; r++) {
        const int row = bm * 128 + wm + mi * 16 + quad * 4 + r;
        D[(size_t)row * DM + col] = v[r] + bvv;
      }
    }
  }
}

// ---------------- flash attention v13: intra-block split-K -----------------
// R8 ablation series: prefetch(+), swizzle(+), setprio(0), dbuf(0), more
// blocks(-). Remaining lever: waves/CU (16 -> 32). 1024-thr blocks, 16 waves:
// group 0 (waves 0-7) handles keys [0,1024), group 1 keys [1024,2048), each
// with its own Ks/Vs (v10's exact swizzle/sigma formulas, 8 tiles each).
// Epilogue: group 1 deposits f32 accO into Ox (aliased on dead Ks/Vs space,
// stride 68 -> 2-lane/bank) + lsums into Lx; barrier; group 0 combines in
// f32, normalizes by 1/(l0+l1), stores. Numerics identical to v10.
__global__ __launch_bounds__(1024, 8)
void attn_kernel(const bf16_t* __restrict__ Q, const bf16_t* __restrict__ K,
                 const bf16_t* __restrict__ Vt, bf16_t* __restrict__ AO) {
  __shared__ __align__(16) char smem[66560];
  bf16_t* Ks  = (bf16_t*)smem;             // [2][128*64] swizzled   (32 KB)
  bf16_t* Vsm = (bf16_t*)(smem + 32768);   // [2][64*128] sigma-swz  (32 KB)
  float*  Lx  = (float*)(smem + 65536);    // [2][128] row sums      (1 KB)
  float*  Ox  = (float*)smem;              // [128][68] f32, epilogue alias

  const int tid  = threadIdx.x;
  const int grp  = tid >> 9;             // 0: keys [0,1024), 1: [1024,2048)
  const int t5   = tid & 511;
  const int w    = (tid >> 6) & 7;       // wave within group, 0..7
  const int lane = tid & 63;
  const int quad = lane >> 4;
  const int lrow = lane & 15;

  const int id  = blockIdx.x;            // 0..511
  const int swz = (id & 7) * 64 + (id >> 3);
  const int bh  = swz >> 4;              // 0..31
  const int q0  = (swz & 15) * 128 + w * 16;

  const bf16_t* Qh  = Q  + (size_t)bh * SEQ * DK;
  const bf16_t* Kh  = K  + (size_t)bh * SEQ * DK;
  const bf16_t* Vth = Vt + (size_t)bh * DK * SEQ;
  const int kofs = grp * 1024;           // this group's key base

  bf16x8_t qf[2];
#pragma unroll
  for (int c = 0; c < 2; c++) {
    bf16x8_t t = *(const bf16x8_t*)(&Qh[(size_t)(q0 + lrow) * DK + c * 32 + quad * 8]);
#pragma unroll
    for (int i = 0; i < 8; i++) t[i] = (bf16_t)((float)t[i] * EXP_C);
    qf[c] = t;
  }

  f32x4_t accO[4] = {};
  float lsum = 0.f;

  const int krow = t5 >> 2;             // 0..127 (K staging row)
  const int kcol = (t5 & 3) * 16;       // elem col
  const int kg0  = (t5 & 3) * 2;        // logical granule (16B units)
  const int vrow = t5 >> 3;             // 0..63 (V staging row)
  const int vcol = (t5 & 7) * 16;       // elem col (group-local key)

  const int kbase = grp * 8192;         // LDS base for this group's Ks/Vs
  const int kw0 = kbase + krow * 64 + ((kg0       ^ (krow & 7)) << 3);
  const int kw1 = kbase + krow * 64 + (((kg0 + 1) ^ (krow & 7)) << 3);
  const int vb  = (vcol >> 5) * 4;           // base granule of 32-key block
  const int vh  = ((vcol >> 4) & 1) * 4;     // elem offset inside granule
  const int vsw = vrow & 15;
  const int vw0 = kbase + vrow * 128 + (((vb + 0) ^ vsw) << 3) + vh;
  const int vw1 = kbase + vrow * 128 + (((vb + 1) ^ vsw) << 3) + vh;
  const int vw2 = kbase + vrow * 128 + (((vb + 2) ^ vsw) << 3) + vh;
  const int vw3 = kbase + vrow * 128 + (((vb + 3) ^ vsw) << 3) + vh;

  // prologue: prefetch this group's tile 0 (named scalars - do not array!)
  uint4 kr0 = *(const uint4*)(&Kh[(size_t)(kofs + krow) * DK + kcol]);
  uint4 kr1 = *(const uint4*)(&Kh[(size_t)(kofs + krow) * DK + kcol + 8]);
  uint4 vr0 = *(const uint4*)(&Vth[(size_t)vrow * SEQ + kofs + vcol]);
  uint4 vr1 = *(const uint4*)(&Vth[(size_t)vrow * SEQ + kofs + vcol + 8]);

  for (int kt = 0; kt < 8; ++kt) {
    // commit prefetched tile to this group's LDS buffers
    *(uint4*)(&Ks[kw0])  = kr0;
    *(uint4*)(&Ks[kw1])  = kr1;
    *(uint2*)(&Vsm[vw0]) = make_uint2(vr0.x, vr0.y);
    *(uint2*)(&Vsm[vw1]) = make_uint2(vr0.z, vr0.w);
    *(uint2*)(&Vsm[vw2]) = make_uint2(vr1.x, vr1.y);
    *(uint2*)(&Vsm[vw3]) = make_uint2(vr1.z, vr1.w);
    __syncthreads();

    // issue next tile's loads; latency hides under this tile's compute
    if (kt + 1 < 8) {
      const int kb = kofs + (kt + 1) * 128;
      kr0 = *(const uint4*)(&Kh[(size_t)(kb + krow) * DK + kcol]);
      kr1 = *(const uint4*)(&Kh[(size_t)(kb + krow) * DK + kcol + 8]);
      vr0 = *(const uint4*)(&Vth[(size_t)vrow * SEQ + kb + vcol]);
      vr1 = *(const uint4*)(&Vth[(size_t)vrow * SEQ + kb + vcol + 8]);
    }

    __builtin_amdgcn_s_setprio(1);
#pragma unroll
    for (int c2 = 0; c2 < 4; ++c2) {        // 32-key chunk
      uint2 pk[2];
#pragma unroll
      for (int kk2 = 0; kk2 < 2; ++kk2) {
        const int kk = c2 * 2 + kk2;        // 16-key tile
        const int krd = kbase + (kk * 16 + lrow) * 64;
        bf16x8_t kf0 = *(const bf16x8_t*)(&Ks[krd + ((quad       ^ (lrow & 7)) << 3)]);
        bf16x8_t kf1 = *(const bf16x8_t*)(&Ks[krd + (((quad + 4) ^ (lrow & 7)) << 3)]);
        f32x4_t z = {};
        z = __builtin_amdgcn_mfma_f32_16x16x32_bf16(kf0, qf[0], z, 0, 0, 0);
        z = __builtin_amdgcn_mfma_f32_16x16x32_bf16(kf1, qf[1], z, 0, 0, 0);
        const float p0 = __builtin_amdgcn_exp2f(z[0]), p1 = __builtin_amdgcn_exp2f(z[1]);
        const float p2 = __builtin_amdgcn_exp2f(z[2]), p3 = __builtin_amdgcn_exp2f(z[3]);
        lsum += (p0 + p1) + (p2 + p3);
        pk[kk2].x = __builtin_amdgcn_perm(__builtin_bit_cast(unsigned, p1),
                                          __builtin_bit_cast(unsigned, p0), 0x07060302u);
        pk[kk2].y = __builtin_amdgcn_perm(__builtin_bit_cast(unsigned, p3),
                                          __builtin_bit_cast(unsigned, p2), 0x07060302u);
      }
      uint4 pfu;
      pfu.x = pk[0].x; pfu.y = pk[0].y; pfu.z = pk[1].x; pfu.w = pk[1].y;
      bf16x8_t pf = __builtin_bit_cast(bf16x8_t, pfu);
#pragma unroll
      for (int nt = 0; nt < 4; ++nt) {
        bf16x8_t vf = *(const bf16x8_t*)(
            &Vsm[kbase + (nt * 16 + lrow) * 128 + ((((c2 << 2) | quad) ^ lrow) << 3)]);
        accO[nt] = __builtin_amdgcn_mfma_f32_16x16x32_bf16(pf, vf, accO[nt], 0, 0, 0);
      }
    }
    __builtin_amdgcn_s_setprio(0);
    __syncthreads();
  }

  // ---- cross-group combine (all f32) ----
  lsum += __shfl_xor(lsum, 16);
  lsum += __shfl_xor(lsum, 32);          // every lane: rowsum(q = lrow), this half
  if (quad == 0) Lx[grp * 128 + w * 16 + lrow] = lsum;

  if (grp == 1) {
#pragma unroll
    for (int nt = 0; nt < 4; nt++)
#pragma unroll
      for (int r = 0; r < 4; r++)
        Ox[(w * 16 + quad * 4 + r) * 68 + nt * 16 + lrow] = accO[nt][r];
  }
  __syncthreads();

  if (grp == 0) {
    const int b = bh >> 4, h = bh & 15;
#pragma unroll
    for (int r = 0; r < 4; r++) {
      const int rl = w * 16 + quad * 4 + r;              // row within 128-tile
      const float linv = 1.0f / (Lx[rl] + Lx[128 + rl]); // l0 + l1 (broadcast)
      const int srowq = q0 + quad * 4 + r;
#pragma unroll
      for (int nt = 0; nt < 4; nt++) {
        const float val = (accO[nt][r] + Ox[rl * 68 + nt * 16 + lrow]) * linv;
        const size_t o = ((size_t)(b * SEQ + srowq)) * DM + h * DK + nt * 16 + lrow;
        AO[o] = (bf16_t)val;
      }
    }
  }
}

extern "C" void kernel_launch(void* const* d_in, const int* in_sizes, int n_in,
                              void* d_out, int out_size, void* d_ws, size_t ws_size,
                              hipStream_t stream) {
  const float* x  = (const float*)d_in[0];
  const float* wq = (const float*)d_in[1];
  const float* bq = (const float*)d_in[2];
  const float* wk = (const float*)d_in[3];
  const float* bk = (const float*)d_in[4];
  const float* wv = (const float*)d_in[5];
  const float* bv = (const float*)d_in[6];
  const float* wo = (const float*)d_in[7];
  const float* bo = (const float*)d_in[8];
  float* out = (float*)d_out;

  char* ws = (char*)d_ws;
  bf16_t* xb   = (bf16_t*)(ws);             // 8 MB
  bf16_t* wqb  = (bf16_t*)(ws + 8388608);   // 2 MB
  bf16_t* wkb  = (bf16_t*)(ws + 10485760);  // 2 MB
  bf16_t* wvb  = (bf16_t*)(ws + 12582912);  // 2 MB
  bf16_t* wob  = (bf16_t*)(ws + 14680064);  // 2 MB
  bf16_t* Qb   = (bf16_t*)(ws + 16777216);  // 8 MB (B,H,S,dk)
  bf16_t* Kb   = (bf16_t*)(ws + 25165824);  // 8 MB (B,H,S,dk)
  bf16_t* Vtb  = (bf16_t*)(ws + 33554432);  // 8 MB (B,H,dk,S)
  bf16_t* AOb  = (bf16_t*)(ws + 41943040);  // 8 MB (B,S,D)
  float2* lut  = (float2*)(ws + 50331648);  // 512 KB RoPE LUT

  prep_kernel<<<8448, 256, 0, stream>>>(x, wq, wk, wv, wo, xb, lut);

  gemm_qkv<<<768, 256, 0, stream>>>(xb, wqb, wkb, wvb, bq, bk, bv, lut, Qb, Kb, Vtb);

  attn_kernel<<<512, 1024, 0, stream>>>(Qb, Kb, Vtb, AOb);

  gemm_out<<<512, 256, 0, stream>>>(AOb, wob, bo, out);
}

// Round 10
// 171.132 us; speedup vs baseline: 1.3944x; 1.3944x over previous
//
#include <hip/hip_runtime.h>
#include <hip/hip_bf16.h>
#include <math.h>

typedef __bf16 bf16_t;
typedef __bf16 bf16x4_t __attribute__((ext_vector_type(4)));
typedef __bf16 bf16x8_t __attribute__((ext_vector_type(8)));
typedef float  f32x4_t  __attribute__((ext_vector_type(4)));

#define SEQ 2048
#define DM  1024
#define NH  16
#define DK  64
// log2(10000)/32
#define ROPE_C 0.4152410118609203f
// log2(e)/sqrt(dk)
#define EXP_C (1.4426950408889634f / 8.0f)

// async global->LDS, 16B per lane; LDS dst = base + lane*16 (wave-uniform base)
#define GLD16(gp, lp) \
  __builtin_amdgcn_global_load_lds((__attribute__((address_space(1))) const void*)(gp), \
                                   (__attribute__((address_space(3))) void*)(lp), 16, 0, 0)

// ---------------- fused prep: fp32->bf16 cast (x,wq,wk,wv,wo) + RoPE LUT ----
__global__ __launch_bounds__(256)
void prep_kernel(const float* __restrict__ x,  const float* __restrict__ wq,
                 const float* __restrict__ wk, const float* __restrict__ wv,
                 const float* __restrict__ wo, bf16_t* __restrict__ dst,
                 float2* __restrict__ lut) {
  if (blockIdx.x < 8192) {
    int i = blockIdx.x * 256 + threadIdx.x;   // float4 index, 0..2097151
    const float* s;
    if (i < 1048576) {
      s = x + (size_t)i * 4;
    } else {
      int j = i - 1048576;
      int w = j >> 18;                        // 262144 float4 per weight
      const float* base = (w == 0) ? wq : (w == 1) ? wk : (w == 2) ? wv : wo;
      s = base + (size_t)(j & 262143) * 4;
    }
    float4 v = *(const float4*)s;
    bf16x4_t o;
    o.x = (bf16_t)v.x; o.y = (bf16_t)v.y; o.z = (bf16_t)v.z; o.w = (bf16_t)v.w;
    ((bf16x4_t*)dst)[i] = o;
  } else {
    int i = (blockIdx.x - 8192) * 256 + threadIdx.x;  // 0..65535
    int s = i >> 5, f = i & 31;
    float ang = (float)s * exp2f(-ROPE_C * (float)f);
    float sn, cs;
    sincosf(ang, &sn, &cs);
    lut[i] = make_float2(sn, cs);
  }
}

// ---------------- fused Q/K/V GEMM: BK=64, swizzled LDS, 768 blocks --------
// (unchanged from R6)
__global__ __launch_bounds__(256, 3)
void gemm_qkv(const bf16_t* __restrict__ A, const bf16_t* __restrict__ Wq,
              const bf16_t* __restrict__ Wk, const bf16_t* __restrict__ Wv,
              const float* __restrict__ bq, const float* __restrict__ bk,
              const float* __restrict__ bv, const float2* __restrict__ lut,
              bf16_t* __restrict__ Qb, bf16_t* __restrict__ Kb,
              bf16_t* __restrict__ Vtb) {
  const int K = 1024;
  __shared__ bf16_t As[128 * 64];           // 16 KB, granule-swizzled
  __shared__ bf16_t Bs[128 * 64];           // 16 KB

  const int tid  = threadIdx.x;
  const int w    = tid >> 6;                // 0..3
  const int lane = tid & 63;
  const int quad = lane >> 4;
  const int lrow = lane & 15;
  const int wm = (w >> 1) * 64, wn = (w & 1) * 64;

  const int srow8 = lane >> 3;                        // 0..7
  const int scolz = (((lane & 7) ^ (lane >> 3)) * 8); // pre-swizzled col

  const int id   = blockIdx.x;              // 0..767
  const int xcd  = id & 7;
  const int rank = id >> 3;                 // 0..95
  const int isV  = rank >= 64;              // block-uniform

  const bf16_t* Ablk;
  const bf16_t* Bblk;
  int bmQK = 0, bnl = 0, isK = 0, bmF = 0, bnT = 0;
  if (!isV) {
    const int q = xcd * 64 + rank;          // 0..511
    bmQK = q >> 4;                          // token tile, [xcd*4, xcd*4+4)
    const int bn = q & 15;
    isK = bn >> 3;                          // 0 = Q, 1 = K
    bnl = bn & 7;
    Ablk = A + (size_t)(bmQK * 128) * K;
    Bblk = (isK ? Wk : Wq) + (size_t)(bnl * 128) * K;
  } else {
    const int v = xcd * 32 + (rank - 64);   // 0..255
    bnT = v >> 3;                           // token tile, [xcd*4, xcd*4+4)
    bmF = v & 7;                            // feature tile 0..7
    Ablk = Wv + (size_t)(bmF * 128) * K;    // 128 feature rows
    Bblk = A + (size_t)(bnT * 128) * K;     // 128 token rows
  }

  f32x4_t acc[4][4] = {};

  for (int k0 = 0; k0 < K; k0 += 64) {
#pragma unroll
    for (int i = 0; i < 4; i++) {
      GLD16(&Ablk[(size_t)(w * 32 + i * 8 + srow8) * K + k0 + scolz], &As[(w * 32 + i * 8) * 64]);
      GLD16(&Bblk[(size_t)(w * 32 + i * 8 + srow8) * K + k0 + scolz], &Bs[(w * 32 + i * 8) * 64]);
    }
    __syncthreads();

#pragma unroll
    for (int kk = 0; kk < 2; kk++) {
      const int gsw = (((kk << 2) | quad) ^ (lrow & 7)) * 8;  // swizzled granule
      bf16x8_t af[4], bf[4];
#pragma unroll
      for (int mi = 0; mi < 4; mi++)
        af[mi] = *(const bf16x8_t*)(&As[(wm + mi * 16 + lrow) * 64 + gsw]);
#pragma unroll
      for (int ni = 0; ni < 4; ni++)
        bf[ni] = *(const bf16x8_t*)(&Bs[(wn + ni * 16 + lrow) * 64 + gsw]);
#pragma unroll
      for (int mi = 0; mi < 4; mi++)
#pragma unroll
        for (int ni = 0; ni < 4; ni++)
          acc[mi][ni] = __builtin_amdgcn_mfma_f32_16x16x32_bf16(af[mi], bf[ni], acc[mi][ni], 0, 0, 0);
    }
    __syncthreads();
  }

  if (!isV) {
    const int brow = bmQK * 128 + wm;
    const int cbase = bnl * 128 + wn;
    const float* bias = isK ? bk : bq;
    bf16_t* D = isK ? Kb : Qb;

#pragma unroll
    for (int ni = 0; ni < 4; ni++) {
      const int col = cbase + ni * 16 + lrow;  // 0..1023
      const float bvv = bias[col];
      const int t = col & 63;
      const int h = col >> 6;
      const int fidx = t >> 1;
#pragma unroll
      for (int mi = 0; mi < 4; mi++) {
        f32x4_t v = acc[mi][ni];
#pragma unroll
        for (int r = 0; r < 4; r++) {
          const int row = brow + mi * 16 + quad * 4 + r;  // token
          const int s = row & (SEQ - 1);
          float val = v[r] + bvv;
          const float2 sc = lut[s * 32 + fidx];
          const float pv = __shfl_xor(val, 1);            // partner column col^1
          val = (t & 1) ? (val * sc.y + pv * sc.x) : (val * sc.y - pv * sc.x);
          const int b = row >> 11;
          const size_t o = (((size_t)(b * NH + h) * SEQ) + s) * DK + t;
          D[o] = (bf16_t)val;
        }
      }
    }
  } else {
    const int fbase = bmF * 128 + wm;
    const int tbase = bnT * 128 + wn;

#pragma unroll
    for (int ni = 0; ni < 4; ni++) {
      const int t = tbase + ni * 16 + lrow;    // token
      const int b = t >> 11;
      const int s = t & (SEQ - 1);
#pragma unroll
      for (int mi = 0; mi < 4; mi++) {
        f32x4_t v = acc[mi][ni];
        const int f = fbase + mi * 16 + quad * 4;  // feature base (mult of 4)
        const int h = f >> 6, d = f & 63;          // d+3 <= 63, never crosses head
#pragma unroll
        for (int r = 0; r < 4; r++)
          Vtb[((size_t)((b * NH + h) * DK + d + r)) * SEQ + s] = (bf16_t)(v[r] + bv[f + r]);
      }
    }
  }
}

// ---------------- output GEMM: BK=64 swizzled (unchanged from R7/R8) -------
__global__ __launch_bounds__(256)
void gemm_out(const bf16_t* __restrict__ A, const bf16_t* __restrict__ Bw,
              const float* __restrict__ bias, float* __restrict__ D) {
  const int K = 1024;
  __shared__ bf16_t As[128 * 64];
  __shared__ bf16_t Bs[64 * 64];

  const int tid  = threadIdx.x;
  const int w    = tid >> 6;                // 0..3
  const int lane = tid & 63;
  const int quad = lane >> 4;
  const int lrow = lane & 15;
  const int wm = (w >> 1) * 64, wn = (w & 1) * 32;

  const int srow8 = lane >> 3;                        // 0..7
  const int scolz = (((lane & 7) ^ (lane >> 3)) * 8); // pre-swizzled col

  const int id  = blockIdx.x;               // 0..511
  const int swz = (id & 7) * 64 + (id >> 3);
  const int bm  = swz >> 4;                 // 0..31
  const int bn  = swz & 15;                 // 0..15

  const bf16_t* Ablk = A  + (size_t)(bm * 128) * K;
  const bf16_t* Bblk = Bw + (size_t)(bn * 64) * K;

  f32x4_t acc[4][2] = {};

  for (int k0 = 0; k0 < K; k0 += 64) {
#pragma unroll
    for (int i = 0; i < 4; i++)
      GLD16(&Ablk[(size_t)(w * 32 + i * 8 + srow8) * K + k0 + scolz], &As[(w * 32 + i * 8) * 64]);
#pragma unroll
    for (int i = 0; i < 2; i++)
      GLD16(&Bblk[(size_t)(w * 16 + i * 8 + srow8) * K + k0 + scolz], &Bs[(w * 16 + i * 8) * 64]);
    __syncthreads();

#pragma unroll
    for (int kk = 0; kk < 2; kk++) {
      const int gsw = (((kk << 2) | quad) ^ (lrow & 7)) * 8;
      bf16x8_t af[4], bf[2];
#pragma unroll
      for (int mi = 0; mi < 4; mi++)
        af[mi] = *(const bf16x8_t*)(&As[(wm + mi * 16 + lrow) * 64 + gsw]);
#pragma unroll
      for (int ni = 0; ni < 2; ni++)
        bf[ni] = *(const bf16x8_t*)(&Bs[(wn + ni * 16 + lrow) * 64 + gsw]);
#pragma unroll
      for (int mi = 0; mi < 4; mi++)
#pragma unroll
        for (int ni = 0; ni < 2; ni++)
          acc[mi][ni] = __builtin_amdgcn_mfma_f32_16x16x32_bf16(af[mi], bf[ni], acc[mi][ni], 0, 0, 0);
    }
    __syncthreads();
  }

#pragma unroll
  for (int ni = 0; ni < 2; ni++) {
    const int col = bn * 64 + wn + ni * 16 + lrow;
    const float bvv = bias[col];
#pragma unroll
    for (int mi = 0; mi < 4; mi++) {
      f32x4_t v = acc[mi][ni];
#pragma unroll
      for (int r = 0; r < 4; r++) {
        const int row = bm * 128 + wm + mi * 16 + quad * 4 + r;
        D[(size_t)row * DM + col] = v[r] + bvv;
      }
    }
  }
}

// ---------------- flash attention v14: 32 q-rows/wave, halved LDS reads ----
// R9 post-mortem: attn is LDS-read-throughput-bound (per CU per tile:
// 16 waves x 32 ds_read_b128 x ~12cy = 6100cy; x16 tiles = 41us of 48.5).
// All 8 waves read IDENTICAL kf/vf fragments; only qf differs. Fix: 4 waves
// x 32 q-rows each (two q-halves A/B per wave). kf read once -> 4 MFMA;
// vf read once -> 2 MFMA. LDS reads/CU halved. Grid 512, QBLK=128 unchanged.
// Staging = R7's 256-thread formulas (correctness-proven). launch_bounds
// (256,2): VGPR cap 256 -> no spill (need ~105); grid gives 2 blocks/CU.
__global__ __launch_bounds__(256, 2)
void attn_kernel(const bf16_t* __restrict__ Q, const bf16_t* __restrict__ K,
                 const bf16_t* __restrict__ Vt, bf16_t* __restrict__ AO) {
  __shared__ bf16_t Ks[128 * 64];        // [key][dk] swizzled, 16 KB
  __shared__ bf16_t Vs[64 * 128];        // [dk][sigma(key)] swizzled, 16 KB

  const int tid  = threadIdx.x;
  const int w    = tid >> 6;             // 0..3
  const int lane = tid & 63;
  const int quad = lane >> 4;
  const int lrow = lane & 15;

  const int id  = blockIdx.x;            // 0..511
  const int swz = (id & 7) * 64 + (id >> 3);
  const int bh  = swz >> 4;              // 0..31
  const int q0  = (swz & 15) * 128 + w * 32;   // wave owns rows [q0, q0+32)

  const bf16_t* Qh  = Q  + (size_t)bh * SEQ * DK;
  const bf16_t* Kh  = K  + (size_t)bh * SEQ * DK;
  const bf16_t* Vth = Vt + (size_t)bh * DK * SEQ;

  bf16x8_t qfA[2], qfB[2];
#pragma unroll
  for (int c = 0; c < 2; c++) {
    bf16x8_t ta = *(const bf16x8_t*)(&Qh[(size_t)(q0 + lrow) * DK + c * 32 + quad * 8]);
    bf16x8_t tb = *(const bf16x8_t*)(&Qh[(size_t)(q0 + 16 + lrow) * DK + c * 32 + quad * 8]);
#pragma unroll
    for (int i = 0; i < 8; i++) {
      ta[i] = (bf16_t)((float)ta[i] * EXP_C);
      tb[i] = (bf16_t)((float)tb[i] * EXP_C);
    }
    qfA[c] = ta; qfB[c] = tb;
  }

  f32x4_t accA[4] = {}, accB[4] = {};
  float lsumA = 0.f, lsumB = 0.f;

  // K staging: 2 threads/row, 4 granules (32 elems) each  [R7 formulas]
  const int krow = tid >> 1;            // 0..127
  const int kcol = (tid & 1) * 32;
  const int kg0  = (tid & 1) * 4;
  const int ksw  = krow & 7;
  const int kwr  = krow * 64;
  const int kw0 = kwr + (((kg0 + 0) ^ ksw) << 3);
  const int kw1 = kwr + (((kg0 + 1) ^ ksw) << 3);
  const int kw2 = kwr + (((kg0 + 2) ^ ksw) << 3);
  const int kw3 = kwr + (((kg0 + 3) ^ ksw) << 3);

  // V staging: 4 threads/row, one 32-key sigma-block (4 granules) each
  const int vrow = tid >> 2;            // 0..63
  const int vcol = (tid & 3) * 32;
  const int vG   = (tid & 3) * 4;
  const int vsw  = vrow & 15;
  const int vwr  = vrow * 128;
  const int vw0 = vwr + (((vG + 0) ^ vsw) << 3);
  const int vw1 = vwr + (((vG + 1) ^ vsw) << 3);
  const int vw2 = vwr + (((vG + 2) ^ vsw) << 3);
  const int vw3 = vwr + (((vG + 3) ^ vsw) << 3);

  // prologue: prefetch tile 0 (named scalars - do not array!)
  uint4 kr0 = *(const uint4*)(&Kh[(size_t)krow * DK + kcol]);
  uint4 kr1 = *(const uint4*)(&Kh[(size_t)krow * DK + kcol + 8]);
  uint4 kr2 = *(const uint4*)(&Kh[(size_t)krow * DK + kcol + 16]);
  uint4 kr3 = *(const uint4*)(&Kh[(size_t)krow * DK + kcol + 24]);
  uint4 vr0 = *(const uint4*)(&Vth[(size_t)vrow * SEQ + vcol]);
  uint4 vr1 = *(const uint4*)(&Vth[(size_t)vrow * SEQ + vcol + 8]);
  uint4 vr2 = *(const uint4*)(&Vth[(size_t)vrow * SEQ + vcol + 16]);
  uint4 vr3 = *(const uint4*)(&Vth[(size_t)vrow * SEQ + vcol + 24]);

  for (int kt = 0; kt < SEQ / 128; ++kt) {
    // commit prefetched tile to LDS (swizzled + sigma-permuted)
    *(uint4*)(&Ks[kw0]) = kr0;
    *(uint4*)(&Ks[kw1]) = kr1;
    *(uint4*)(&Ks[kw2]) = kr2;
    *(uint4*)(&Ks[kw3]) = kr3;
    // sigma: keys [0..16) -> elems 0-3 of granules G+0..3; [16..32) -> elems 4-7
    *(uint2*)(&Vs[vw0])     = make_uint2(vr0.x, vr0.y);
    *(uint2*)(&Vs[vw1])     = make_uint2(vr0.z, vr0.w);
    *(uint2*)(&Vs[vw2])     = make_uint2(vr1.x, vr1.y);
    *(uint2*)(&Vs[vw3])     = make_uint2(vr1.z, vr1.w);
    *(uint2*)(&Vs[vw0 + 4]) = make_uint2(vr2.x, vr2.y);
    *(uint2*)(&Vs[vw1 + 4]) = make_uint2(vr2.z, vr2.w);
    *(uint2*)(&Vs[vw2 + 4]) = make_uint2(vr3.x, vr3.y);
    *(uint2*)(&Vs[vw3 + 4]) = make_uint2(vr3.z, vr3.w);
    __syncthreads();

    // issue next tile's loads; latency hides under this tile's compute
    if (kt + 1 < SEQ / 128) {
      const int kb = (kt + 1) * 128;
      kr0 = *(const uint4*)(&Kh[(size_t)(kb + krow) * DK + kcol]);
      kr1 = *(const uint4*)(&Kh[(size_t)(kb + krow) * DK + kcol + 8]);
      kr2 = *(const uint4*)(&Kh[(size_t)(kb + krow) * DK + kcol + 16]);
      kr3 = *(const uint4*)(&Kh[(size_t)(kb + krow) * DK + kcol + 24]);
      vr0 = *(const uint4*)(&Vth[(size_t)vrow * SEQ + kb + vcol]);
      vr1 = *(const uint4*)(&Vth[(size_t)vrow * SEQ + kb + vcol + 8]);
      vr2 = *(const uint4*)(&Vth[(size_t)vrow * SEQ + kb + vcol + 16]);
      vr3 = *(const uint4*)(&Vth[(size_t)vrow * SEQ + kb + vcol + 24]);
    }

    __builtin_amdgcn_s_setprio(1);
#pragma unroll
    for (int c2 = 0; c2 < 4; ++c2) {        // 32-key chunk
      uint2 pkA[2], pkB[2];
#pragma unroll
      for (int kk2 = 0; kk2 < 2; ++kk2) {
        const int kk = c2 * 2 + kk2;        // 16-key tile
        const int krd = (kk * 16 + lrow) * 64;
        bf16x8_t kf0 = *(const bf16x8_t*)(&Ks[krd + ((quad       ^ (lrow & 7)) << 3)]);
        bf16x8_t kf1 = *(const bf16x8_t*)(&Ks[krd + (((quad + 4) ^ (lrow & 7)) << 3)]);
        f32x4_t zA = {}, zB = {};
        zA = __builtin_amdgcn_mfma_f32_16x16x32_bf16(kf0, qfA[0], zA, 0, 0, 0);
        zA = __builtin_amdgcn_mfma_f32_16x16x32_bf16(kf1, qfA[1], zA, 0, 0, 0);
        zB = __builtin_amdgcn_mfma_f32_16x16x32_bf16(kf0, qfB[0], zB, 0, 0, 0);
        zB = __builtin_amdgcn_mfma_f32_16x16x32_bf16(kf1, qfB[1], zB, 0, 0, 0);
        const float a0 = __builtin_amdgcn_exp2f(zA[0]), a1 = __builtin_amdgcn_exp2f(zA[1]);
        const float a2 = __builtin_amdgcn_exp2f(zA[2]), a3 = __builtin_amdgcn_exp2f(zA[3]);
        const float b0 = __builtin_amdgcn_exp2f(zB[0]), b1 = __builtin_amdgcn_exp2f(zB[1]);
        const float b2 = __builtin_amdgcn_exp2f(zB[2]), b3 = __builtin_amdgcn_exp2f(zB[3]);
        lsumA += (a0 + a1) + (a2 + a3);
        lsumB += (b0 + b1) + (b2 + b3);
        pkA[kk2].x = __builtin_amdgcn_perm(__builtin_bit_cast(unsigned, a1),
                                           __builtin_bit_cast(unsigned, a0), 0x07060302u);
        pkA[kk2].y = __builtin_amdgcn_perm(__builtin_bit_cast(unsigned, a3),
                                           __builtin_bit_cast(unsigned, a2), 0x07060302u);
        pkB[kk2].x = __builtin_amdgcn_perm(__builtin_bit_cast(unsigned, b1),
                                           __builtin_bit_cast(unsigned, b0), 0x07060302u);
        pkB[kk2].y = __builtin_amdgcn_perm(__builtin_bit_cast(unsigned, b3),
                                           __builtin_bit_cast(unsigned, b2), 0x07060302u);
      }
      uint4 pfuA, pfuB;
      pfuA.x = pkA[0].x; pfuA.y = pkA[0].y; pfuA.z = pkA[1].x; pfuA.w = pkA[1].y;
      pfuB.x = pkB[0].x; pfuB.y = pkB[0].y; pfuB.z = pkB[1].x; pfuB.w = pkB[1].y;
      bf16x8_t pfA = __builtin_bit_cast(bf16x8_t, pfuA);
      bf16x8_t pfB = __builtin_bit_cast(bf16x8_t, pfuB);
#pragma unroll
      for (int nt = 0; nt < 4; ++nt) {
        // sigma-permuted V: lane's 8 key-slots contiguous at granule c2*4+quad
        bf16x8_t vf = *(const bf16x8_t*)(
            &Vs[(nt * 16 + lrow) * 128 + ((((c2 << 2) | quad) ^ lrow) << 3)]);
        accA[nt] = __builtin_amdgcn_mfma_f32_16x16x32_bf16(pfA, vf, accA[nt], 0, 0, 0);
        accB[nt] = __builtin_amdgcn_mfma_f32_16x16x32_bf16(pfB, vf, accB[nt], 0, 0, 0);
      }
    }
    __builtin_amdgcn_s_setprio(0);
    __syncthreads();
  }

  lsumA += __shfl_xor(lsumA, 16);
  lsumA += __shfl_xor(lsumA, 32);
  lsumB += __shfl_xor(lsumB, 16);
  lsumB += __shfl_xor(lsumB, 32);
  float linvA[4], linvB[4];
#pragma unroll
  for (int r = 0; r < 4; r++) {
    linvA[r] = 1.0f / __shfl(lsumA, quad * 4 + r);
    linvB[r] = 1.0f / __shfl(lsumB, quad * 4 + r);
  }

  const int b = bh >> 4, h = bh & 15;
#pragma unroll
  for (int nt = 0; nt < 4; nt++)
#pragma unroll
    for (int r = 0; r < 4; r++) {
      const int rowA = q0 + quad * 4 + r;
      const int rowB = q0 + 16 + quad * 4 + r;
      const float va = accA[nt][r] * linvA[r];
      const float vb = accB[nt][r] * linvB[r];
      AO[((size_t)(b * SEQ + rowA)) * DM + h * DK + nt * 16 + lrow] = (bf16_t)va;
      AO[((size_t)(b * SEQ + rowB)) * DM + h * DK + nt * 16 + lrow] = (bf16_t)vb;
    }
}

extern "C" void kernel_launch(void* const* d_in, const int* in_sizes, int n_in,
                              void* d_out, int out_size, void* d_ws, size_t ws_size,
                              hipStream_t stream) {
  const float* x  = (const float*)d_in[0];
  const float* wq = (const float*)d_in[1];
  const float* bq = (const float*)d_in[2];
  const float* wk = (const float*)d_in[3];
  const float* bk = (const float*)d_in[4];
  const float* wv = (const float*)d_in[5];
  const float* bv = (const float*)d_in[6];
  const float* wo = (const float*)d_in[7];
  const float* bo = (const float*)d_in[8];
  float* out = (float*)d_out;

  char* ws = (char*)d_ws;
  bf16_t* xb   = (bf16_t*)(ws);             // 8 MB
  bf16_t* wqb  = (bf16_t*)(ws + 8388608);   // 2 MB
  bf16_t* wkb  = (bf16_t*)(ws + 10485760);  // 2 MB
  bf16_t* wvb  = (bf16_t*)(ws + 12582912);  // 2 MB
  bf16_t* wob  = (bf16_t*)(ws + 14680064);  // 2 MB
  bf16_t* Qb   = (bf16_t*)(ws + 16777216);  // 8 MB (B,H,S,dk)
  bf16_t* Kb   = (bf16_t*)(ws + 25165824);  // 8 MB (B,H,S,dk)
  bf16_t* Vtb  = (bf16_t*)(ws + 33554432);  // 8 MB (B,H,dk,S)
  bf16_t* AOb  = (bf16_t*)(ws + 41943040);  // 8 MB (B,S,D)
  float2* lut  = (float2*)(ws + 50331648);  // 512 KB RoPE LUT

  prep_kernel<<<8448, 256, 0, stream>>>(x, wq, wk, wv, wo, xb, lut);

  gemm_qkv<<<768, 256, 0, stream>>>(xb, wqb, wkb, wvb, bq, bk, bv, lut, Qb, Kb, Vtb);

  attn_kernel<<<512, 256, 0, stream>>>(Qb, Kb, Vtb, AOb);

  gemm_out<<<512, 256, 0, stream>>>(AOb, wob, bo, out);
}